// Round 5
// baseline (2747.424 us; speedup 1.0000x reference)
//
#include <hip/hip_runtime.h>
#include <hip/hip_bf16.h>

// UnifiedCoreFlow: 24x { gather-cols -> GEMM(1024^3) -> clip -> quantize } -> 10-col gather.
// R5 restructure (from R4 evidence: ~28us/GEMM, latency/structure-bound):
//  - wsplit_k: ALL W pre-split fp32 -> bf16 hi+lo ONCE (removes hot-loop VALU convert,
//    enables global_load_lds 16B staging).
//  - gather_k per layer: G = H[:, idx] coalesced pre-pass (GEMM LDS drops 148KB->96KB).
//  - gemm_k: 256 wgs x 64b x 64o, BK=64, 16 K-steps, 4-deep global_load_lds ring with
//    COUNTED vmcnt (issue s+3, wait vmcnt(2*LOADS), raw s_barrier; never vmcnt(0) mid-loop).
//  - 16B-chunk XOR swizzle (chunk ^= row&7), applied on pre-swizzled global source AND
//    frag reads (both-sides rule) -> uniform bank-quad load = LDS floor.
//  - Fragment maps / accumulation order / epilogue identical to the R4 passing kernel
//    (absmax 0.0) -> bitwise-same numerics.

#define N_DIM   1024
#define NSTEP   16          // K / 64
#define THREADS 512

typedef __attribute__((ext_vector_type(8))) __bf16 bf16x8;
typedef __attribute__((ext_vector_type(4))) float  f32x4;
typedef unsigned short u16;

__device__ __forceinline__ u16 f2bf(float f) {
  __hip_bfloat16 h = __float2bfloat16(f);
  return __builtin_bit_cast(u16, h);
}
__device__ __forceinline__ float bf2f(u16 u) {
  __hip_bfloat16 h = __builtin_bit_cast(__hip_bfloat16, u);
  return __bfloat162float(h);
}
__device__ __forceinline__ float tq_val(const int* p) {
  int v = *p;
  if (v >= 1 && v <= (1 << 24)) return (float)v;
  return __builtin_bit_cast(float, v);
}
__device__ __forceinline__ void gload16(const void* g, void* l) {
  __builtin_amdgcn_global_load_lds(
      (const __attribute__((address_space(1))) unsigned int*)g,
      (__attribute__((address_space(3))) unsigned int*)l, 16, 0, 0);
}
template <int N>
__device__ __forceinline__ void wait_vm() {
  asm volatile("s_waitcnt vmcnt(%0)" :: "n"(N) : "memory");
}

// ---- one-time W split: fp32 -> bf16 hi + lo ------------------------------
__global__ __launch_bounds__(256)
void wsplit_k(const float* __restrict__ W, u16* __restrict__ Wh,
              u16* __restrict__ Wl, int n4) {
  int i = blockIdx.x * blockDim.x + threadIdx.x;
  const int stride = gridDim.x * blockDim.x;
  for (; i < n4; i += stride) {
    float4 v = ((const float4*)W)[i];
    ushort4 h, l;
    h.x = f2bf(v.x); l.x = f2bf(v.x - bf2f(h.x));
    h.y = f2bf(v.y); l.y = f2bf(v.y - bf2f(h.y));
    h.z = f2bf(v.z); l.z = f2bf(v.z - bf2f(h.z));
    h.w = f2bf(v.w); l.w = f2bf(v.w - bf2f(h.w));
    ((ushort4*)Wh)[i] = h;
    ((ushort4*)Wl)[i] = l;
  }
}

// ---- layer-0 pre-pass: gather x by idx0, split hi/lo ---------------------
__global__ __launch_bounds__(256)
void xsplit_k(const float* __restrict__ x, const int* __restrict__ gidx0,
              u16* __restrict__ G0h, u16* __restrict__ G0l) {
  __shared__ float row[N_DIM];
  const int b = blockIdx.x, t = threadIdx.x;
  *(float4*)&row[t * 4] = *(const float4*)&x[(size_t)b * N_DIM + t * 4];
  __syncthreads();
  const int i0 = t * 4;
  const int4 c = *(const int4*)&gidx0[i0];
  float v0 = row[c.x], v1 = row[c.y], v2 = row[c.z], v3 = row[c.w];
  u16 h0 = f2bf(v0), h1 = f2bf(v1), h2 = f2bf(v2), h3 = f2bf(v3);
  u16 l0 = f2bf(v0 - bf2f(h0)), l1 = f2bf(v1 - bf2f(h1));
  u16 l2 = f2bf(v2 - bf2f(h2)), l3 = f2bf(v3 - bf2f(h3));
  *(ushort4*)&G0h[(size_t)b * N_DIM + i0] = make_ushort4(h0, h1, h2, h3);
  *(ushort4*)&G0l[(size_t)b * N_DIM + i0] = make_ushort4(l0, l1, l2, l3);
}

// ---- per-layer gather: G = H[:, idx] (bf16 k-values, exact) --------------
__global__ __launch_bounds__(256)
void gather_k(const u16* __restrict__ H, const int* __restrict__ idx,
              u16* __restrict__ G) {
  __shared__ u16 rows[4][N_DIM];
  const int t = threadIdx.x;
  const int r0 = blockIdx.x * 4;
  const int4* src = (const int4*)(H + (size_t)r0 * N_DIM);
  int4* dst = (int4*)&rows[0][0];
  dst[t] = src[t];
  dst[t + 256] = src[t + 256];
  __syncthreads();
  const int4 iv = *(const int4*)&idx[t * 4];
  #pragma unroll
  for (int rr = 0; rr < 4; ++rr) {
    ushort4 o;
    o.x = rows[rr][iv.x]; o.y = rows[rr][iv.y];
    o.z = rows[rr][iv.z]; o.w = rows[rr][iv.w];
    *(ushort4*)&G[(size_t)(r0 + rr) * N_DIM + t * 4] = o;
  }
}

// ---- pipelined GEMM ------------------------------------------------------
// MODE 0: A = G0h+G0l (layer 0, 4-term product). 1: mid. 2: last (B rows = W[oidx]).
// Tiles per stage (8KB each, [64 rows][64 halves], 16B-chunk XOR swizzled):
//   [A][A2 (mode0 only)][Bh][Bl]; 4-stage ring.
template <int MODE>
__global__ __launch_bounds__(THREADS, 1)
void gemm_k(const u16* __restrict__ A0, const u16* __restrict__ A1,
            const u16* __restrict__ Wh, const u16* __restrict__ Wl,
            const int* __restrict__ oidx,
            const float* __restrict__ scales, const int* __restrict__ tqp,
            int l, int n_out,
            u16* __restrict__ Hout, float* __restrict__ out) {
  constexpr int LOADS = (MODE == 0) ? 4 : 3;
  constexpr int STAGE = LOADS * 8192;
  extern __shared__ char sm[];

  const int t  = threadIdx.x;
  const int b0 = blockIdx.x * 64;
  const int o0 = blockIdx.y * 64;

  // staging map: thread t -> tile row r=t>>3, chunk c=t&7; LDS linear (t*16),
  // global source pre-swizzled: chunk c ^ (r&7).
  const int r  = t >> 3;
  const int cs = ((t & 7) ^ (r & 7)) * 16;
  const char* gA0 = (const char*)(A0 + (size_t)(b0 + r) * N_DIM) + cs;
  const char* gA1 = nullptr;
  if constexpr (MODE == 0) gA1 = (const char*)(A1 + (size_t)(b0 + r) * N_DIM) + cs;
  int orow = o0 + r;
  if constexpr (MODE == 2) orow = oidx[r < n_out ? r : 0];
  const char* gBh = (const char*)(Wh + (size_t)orow * N_DIM) + cs;
  const char* gBl = (const char*)(Wl + (size_t)orow * N_DIM) + cs;

  auto issue = [&](int st) {
    const int k0b = st * 128;                  // 64 halves per stage along k
    char* base = sm + (st & 3) * STAGE;
    gload16(gA0 + k0b, base + t * 16);
    if constexpr (MODE == 0) gload16(gA1 + k0b, base + 8192 + t * 16);
    gload16(gBh + k0b, base + (LOADS - 2) * 8192 + t * 16);
    gload16(gBl + k0b, base + (LOADS - 1) * 8192 + t * 16);
  };

  // fragment read offsets (same lane conventions as the verified R4 kernel)
  const int lane = t & 63, w = t >> 6;
  const int ln = lane & 15, g = lane >> 4;
  const int wm = w >> 1, wn = w & 1;
  const int arow = wm * 16 + ln;
  const int aoff0 = arow * 128 + ((g       ^ (arow & 7)) * 16);  // kc=0
  const int aoff1 = arow * 128 + (((4 + g) ^ (arow & 7)) * 16);  // kc=1
  const int br0 = wn * 32 + ln, br1 = wn * 32 + 16 + ln;
  const int bo00 = br0 * 128 + ((g       ^ (br0 & 7)) * 16);
  const int bo01 = br0 * 128 + (((4 + g) ^ (br0 & 7)) * 16);
  const int bo10 = br1 * 128 + ((g       ^ (br1 & 7)) * 16);
  const int bo11 = br1 * 128 + (((4 + g) ^ (br1 & 7)) * 16);

  issue(0); issue(1); issue(2);

  f32x4 acc0 = {0.f, 0.f, 0.f, 0.f};
  f32x4 acc1 = {0.f, 0.f, 0.f, 0.f};

  for (int s = 0; s < NSTEP; ++s) {
    if (s < NSTEP - 2)       wait_vm<2 * LOADS>();   // stage s drained, 2 in flight
    else if (s == NSTEP - 2) wait_vm<LOADS>();
    else                     wait_vm<0>();
    __builtin_amdgcn_s_barrier();
    __builtin_amdgcn_sched_barrier(0);

    const char* base = sm + (s & 3) * STAGE;
    const char* tBh  = base + (LOADS - 2) * 8192;
    const char* tBl  = base + (LOADS - 1) * 8192;
    bf16x8 a0 = *(const bf16x8*)(base + aoff0);
    bf16x8 a1 = *(const bf16x8*)(base + aoff1);
    bf16x8 bh00 = *(const bf16x8*)(tBh + bo00), bl00 = *(const bf16x8*)(tBl + bo00);
    bf16x8 bh10 = *(const bf16x8*)(tBh + bo10), bl10 = *(const bf16x8*)(tBl + bo10);
    bf16x8 bh01 = *(const bf16x8*)(tBh + bo01), bl01 = *(const bf16x8*)(tBl + bo01);
    bf16x8 bh11 = *(const bf16x8*)(tBh + bo11), bl11 = *(const bf16x8*)(tBl + bo11);

    acc0 = __builtin_amdgcn_mfma_f32_16x16x32_bf16(a0, bh00, acc0, 0, 0, 0);
    acc0 = __builtin_amdgcn_mfma_f32_16x16x32_bf16(a0, bl00, acc0, 0, 0, 0);
    acc1 = __builtin_amdgcn_mfma_f32_16x16x32_bf16(a0, bh10, acc1, 0, 0, 0);
    acc1 = __builtin_amdgcn_mfma_f32_16x16x32_bf16(a0, bl10, acc1, 0, 0, 0);
    if constexpr (MODE == 0) {
      bf16x8 a20 = *(const bf16x8*)(base + 8192 + aoff0);
      acc0 = __builtin_amdgcn_mfma_f32_16x16x32_bf16(a20, bh00, acc0, 0, 0, 0);
      acc0 = __builtin_amdgcn_mfma_f32_16x16x32_bf16(a20, bl00, acc0, 0, 0, 0);
      acc1 = __builtin_amdgcn_mfma_f32_16x16x32_bf16(a20, bh10, acc1, 0, 0, 0);
      acc1 = __builtin_amdgcn_mfma_f32_16x16x32_bf16(a20, bl10, acc1, 0, 0, 0);
    }
    acc0 = __builtin_amdgcn_mfma_f32_16x16x32_bf16(a1, bh01, acc0, 0, 0, 0);
    acc0 = __builtin_amdgcn_mfma_f32_16x16x32_bf16(a1, bl01, acc0, 0, 0, 0);
    acc1 = __builtin_amdgcn_mfma_f32_16x16x32_bf16(a1, bh11, acc1, 0, 0, 0);
    acc1 = __builtin_amdgcn_mfma_f32_16x16x32_bf16(a1, bl11, acc1, 0, 0, 0);
    if constexpr (MODE == 0) {
      bf16x8 a21 = *(const bf16x8*)(base + 8192 + aoff1);
      acc0 = __builtin_amdgcn_mfma_f32_16x16x32_bf16(a21, bh01, acc0, 0, 0, 0);
      acc0 = __builtin_amdgcn_mfma_f32_16x16x32_bf16(a21, bl01, acc0, 0, 0, 0);
      acc1 = __builtin_amdgcn_mfma_f32_16x16x32_bf16(a21, bh11, acc1, 0, 0, 0);
      acc1 = __builtin_amdgcn_mfma_f32_16x16x32_bf16(a21, bl11, acc1, 0, 0, 0);
    }

    if (s < NSTEP - 3) issue(s + 3);   // overwrites buf[(s-1)&3]: all compute(s-1) done
  }

  // epilogue (identical to R4): y = acc*pf; clip [0,sl]; k = rint(y*Tq/sl)
  const float Tqf = tq_val(tqp);
  const float sl  = scales[l];
  const float pf  = (l == 0) ? 1.0f : scales[l - 1] / Tqf;
  const float rq  = Tqf / sl;
  const float fq  = sl / Tqf;

  f32x4 accs[2] = {acc0, acc1};
  #pragma unroll
  for (int fn = 0; fn < 2; ++fn) {
    const int ocl = wn * 32 + fn * 16 + ln;      // C/D col = lane&15
    #pragma unroll
    for (int rr = 0; rr < 4; ++rr) {
      const int br = b0 + wm * 16 + g * 4 + rr;  // C/D row = 4*(lane>>4)+reg
      float y = accs[fn][rr] * pf;
      y = fminf(fmaxf(y, 0.0f), sl);
      float kq = rintf(y * rq);
      if constexpr (MODE == 2) {
        if (ocl < n_out) out[(size_t)br * n_out + ocl] = kq * fq;
      } else {
        Hout[(size_t)br * N_DIM + (o0 + ocl)] = f2bf(kq);
      }
    }
  }
}

extern "C" void kernel_launch(void* const* d_in, const int* in_sizes, int n_in,
                              void* d_out, int out_size, void* d_ws, size_t ws_size,
                              hipStream_t stream) {
  const float* x      = (const float*)d_in[0];
  const float* W      = (const float*)d_in[1];
  const int*   gidx   = (const int*)d_in[2];
  const float* scales = (const float*)d_in[3];
  const int*   oidx   = (const int*)d_in[4];
  const int*   tqp    = (const int*)d_in[5];
  float*       out    = (float*)d_out;
  const int L     = in_sizes[3];
  const int n_out = in_sizes[4];
  const size_t NN = (size_t)N_DIM * N_DIM;

  u16* Whi = (u16*)d_ws;
  u16* Wlo = Whi + (size_t)L * NN;
  u16* G0h = Wlo + (size_t)L * NN;
  u16* G0l = G0h + NN;
  u16* G   = G0l + NN;
  u16* H   = G + NN;

  hipFuncSetAttribute((const void*)&gemm_k<0>, hipFuncAttributeMaxDynamicSharedMemorySize, 131072);
  hipFuncSetAttribute((const void*)&gemm_k<1>, hipFuncAttributeMaxDynamicSharedMemorySize, 98304);
  hipFuncSetAttribute((const void*)&gemm_k<2>, hipFuncAttributeMaxDynamicSharedMemorySize, 98304);

  wsplit_k<<<2048, 256, 0, stream>>>(W, Whi, Wlo, (int)(L * NN / 4));
  xsplit_k<<<1024, 256, 0, stream>>>(x, gidx, G0h, G0l);

  gemm_k<0><<<dim3(16, 16), THREADS, 131072, stream>>>(
      G0h, G0l, Whi, Wlo, nullptr, scales, tqp, 0, n_out, H, nullptr);

  for (int l = 1; l < L; ++l) {
    gather_k<<<256, 256, 0, stream>>>(H, gidx + (size_t)l * N_DIM, G);
    if (l < L - 1) {
      gemm_k<1><<<dim3(16, 16), THREADS, 98304, stream>>>(
          G, nullptr, Whi + (size_t)l * NN, Wlo + (size_t)l * NN,
          nullptr, scales, tqp, l, n_out, H, nullptr);
    } else {
      gemm_k<2><<<dim3(16, 1), THREADS, 98304, stream>>>(
          G, nullptr, Whi + (size_t)l * NN, Wlo + (size_t)l * NN,
          oidx, scales, tqp, l, n_out, nullptr, out);
    }
  }
}

// Round 7
// 1158.411 us; speedup vs baseline: 2.3717x; 2.3717x over previous
//
#include <hip/hip_runtime.h>
#include <hip/hip_bf16.h>

// UnifiedCoreFlow: 24x { gather-cols -> GEMM(1024^3) -> clip -> quantize } -> 10-col gather.
// R6 (from R5 post-mortem: 121us/gemm, 99% vmcnt-stalled, barrier-convoyed at 1 wg/CU,
//     L2 thrash from 16x panel re-fetch):
//  - GEMM has NO LDS and NO barriers: A/B MFMA fragments are loaded directly from global
//    (16B/lane, 64B-coalesced rows, L1-dedup across waves), 4-deep register prefetch ring,
//    fully unrolled (compile-time indices -> no scratch). 8 waves free-run per CU.
//  - XCD-exclusive o-panels: wg i -> XCD i&7 owns o-panels {2(i&7), 2(i&7)+1}, all b.
//    Per-XCD set = 512KB W + streaming A < 4MB L2 -> W fetched from HBM once chip-wide.
//  - wsplit_k pre-splits W fp32 -> bf16 hi+lo once; gather_k per layer; activations are
//    exact integers k in [0,16] in bf16. MFMA order + epilogue identical to the R4
//    absmax-0.0 kernel.

#define N_DIM   1024
#define THREADS 512

typedef __attribute__((ext_vector_type(8))) __bf16 bf16x8;
typedef __attribute__((ext_vector_type(4))) float  f32x4;
typedef unsigned short u16;

__device__ __forceinline__ u16 f2bf(float f) {
  __hip_bfloat16 h = __float2bfloat16(f);
  return __builtin_bit_cast(u16, h);
}
__device__ __forceinline__ float bf2f(u16 u) {
  __hip_bfloat16 h = __builtin_bit_cast(__hip_bfloat16, u);
  return __bfloat162float(h);
}
__device__ __forceinline__ float tq_val(const int* p) {
  int v = *p;
  if (v >= 1 && v <= (1 << 24)) return (float)v;
  return __builtin_bit_cast(float, v);
}

// ---- one-time W split: fp32 -> bf16 hi + lo ------------------------------
__global__ __launch_bounds__(256)
void wsplit_k(const float* __restrict__ W, u16* __restrict__ Wh,
              u16* __restrict__ Wl, int n4) {
  int i = blockIdx.x * blockDim.x + threadIdx.x;
  const int stride = gridDim.x * blockDim.x;
  for (; i < n4; i += stride) {
    float4 v = ((const float4*)W)[i];
    ushort4 h, l;
    h.x = f2bf(v.x); l.x = f2bf(v.x - bf2f(h.x));
    h.y = f2bf(v.y); l.y = f2bf(v.y - bf2f(h.y));
    h.z = f2bf(v.z); l.z = f2bf(v.z - bf2f(h.z));
    h.w = f2bf(v.w); l.w = f2bf(v.w - bf2f(h.w));
    ((ushort4*)Wh)[i] = h;
    ((ushort4*)Wl)[i] = l;
  }
}

// ---- layer-0 pre-pass: gather x by idx0, split hi/lo ---------------------
__global__ __launch_bounds__(256)
void xsplit_k(const float* __restrict__ x, const int* __restrict__ gidx0,
              u16* __restrict__ G0h, u16* __restrict__ G0l) {
  __shared__ float row[N_DIM];
  const int b = blockIdx.x, t = threadIdx.x;
  *(float4*)&row[t * 4] = *(const float4*)&x[(size_t)b * N_DIM + t * 4];
  __syncthreads();
  const int i0 = t * 4;
  const int4 c = *(const int4*)&gidx0[i0];
  float v0 = row[c.x], v1 = row[c.y], v2 = row[c.z], v3 = row[c.w];
  u16 h0 = f2bf(v0), h1 = f2bf(v1), h2 = f2bf(v2), h3 = f2bf(v3);
  u16 l0 = f2bf(v0 - bf2f(h0)), l1 = f2bf(v1 - bf2f(h1));
  u16 l2 = f2bf(v2 - bf2f(h2)), l3 = f2bf(v3 - bf2f(h3));
  *(ushort4*)&G0h[(size_t)b * N_DIM + i0] = make_ushort4(h0, h1, h2, h3);
  *(ushort4*)&G0l[(size_t)b * N_DIM + i0] = make_ushort4(l0, l1, l2, l3);
}

// ---- per-layer gather: G = H[:, idx] (bf16 k-values, exact) --------------
__global__ __launch_bounds__(256)
void gather_k(const u16* __restrict__ H, const int* __restrict__ idx,
              u16* __restrict__ G) {
  __shared__ u16 rows[4][N_DIM];
  const int t = threadIdx.x;
  const int r0 = blockIdx.x * 4;
  const int4* src = (const int4*)(H + (size_t)r0 * N_DIM);
  int4* dst = (int4*)&rows[0][0];
  dst[t] = src[t];
  dst[t + 256] = src[t + 256];
  __syncthreads();
  const int4 iv = *(const int4*)&idx[t * 4];
  #pragma unroll
  for (int rr = 0; rr < 4; ++rr) {
    ushort4 o;
    o.x = rows[rr][iv.x]; o.y = rows[rr][iv.y];
    o.z = rows[rr][iv.z]; o.w = rows[rr][iv.w];
    *(ushort4*)&G[(size_t)(r0 + rr) * N_DIM + t * 4] = o;
  }
}

// ---- barrier-free direct-fragment GEMM -----------------------------------
// MODE 0: A = G0h+G0l (layer 0). 1: mid. 2: last (B rows = W[oidx], 16 wgs).
// 64b x 64o per wg; wave (wm,wn) tile 16b x 32o; frag lane (ln,g).
#define MFMA(d, va, vb) d = __builtin_amdgcn_mfma_f32_16x16x32_bf16(va, vb, d, 0, 0, 0)

template <int MODE>
__global__ __launch_bounds__(THREADS, 1)
void gemm_k(const u16* __restrict__ A0, const u16* __restrict__ A1,
            const u16* __restrict__ Wh, const u16* __restrict__ Wl,
            const int* __restrict__ oidx,
            const float* __restrict__ scales, const int* __restrict__ tqp,
            int l, int n_out,
            u16* __restrict__ Hout, float* __restrict__ out) {
  const int t = threadIdx.x;
  const int i = blockIdx.x;
  int b0, o0;
  if constexpr (MODE == 2) {
    b0 = i * 64; o0 = 0;
  } else {
    // XCD-exclusive o-panels: XCD (i&7) owns o-panels {2(i&7), 2(i&7)+1}, all b.
    const int xcd = i & 7, j = i >> 3;
    o0 = (xcd * 2 + (j & 1)) * 64;
    b0 = (j >> 1) * 64;
  }

  const int lane = t & 63, w = t >> 6;
  const int ln = lane & 15, g = lane >> 4;
  const int wm = w >> 1, wn = w & 1;

  const u16* pA = A0 + (size_t)(b0 + wm * 16 + ln) * N_DIM + g * 8;
  const u16* pA2 = nullptr;
  if constexpr (MODE == 0) pA2 = A1 + (size_t)(b0 + wm * 16 + ln) * N_DIM + g * 8;

  int orow0 = o0 + wn * 32 + ln;
  int orow1 = orow0 + 16;
  if constexpr (MODE == 2) {
    const int c0 = wn * 32 + ln, c1 = c0 + 16;
    orow0 = oidx[c0 < n_out ? c0 : 0];
    orow1 = oidx[c1 < n_out ? c1 : 0];
  }
  const u16* pBh0 = Wh + (size_t)orow0 * N_DIM + g * 8;
  const u16* pBl0 = Wl + (size_t)orow0 * N_DIM + g * 8;
  const u16* pBh1 = Wh + (size_t)orow1 * N_DIM + g * 8;
  const u16* pBl1 = Wl + (size_t)orow1 * N_DIM + g * 8;

  f32x4 acc0 = {0.f, 0.f, 0.f, 0.f};
  f32x4 acc1 = {0.f, 0.f, 0.f, 0.f};

  // 4-deep register prefetch ring, fully unrolled (all indices compile-time).
  bf16x8 va[4], vbh0[4], vbl0[4], vbh1[4], vbl1[4];
  bf16x8 va2[4];
  #pragma unroll
  for (int d = 0; d < 4; ++d) {
    va[d]   = *(const bf16x8*)(pA   + d * 32);
    vbh0[d] = *(const bf16x8*)(pBh0 + d * 32);
    vbl0[d] = *(const bf16x8*)(pBl0 + d * 32);
    vbh1[d] = *(const bf16x8*)(pBh1 + d * 32);
    vbl1[d] = *(const bf16x8*)(pBl1 + d * 32);
    if constexpr (MODE == 0) va2[d] = *(const bf16x8*)(pA2 + d * 32);
  }

  #pragma unroll
  for (int s = 0; s < 32; ++s) {
    const int p = s & 3;
    // same per-accumulator addition order as the verified R4 kernel
    MFMA(acc0, va[p], vbh0[p]);
    MFMA(acc0, va[p], vbl0[p]);
    MFMA(acc1, va[p], vbh1[p]);
    MFMA(acc1, va[p], vbl1[p]);
    if constexpr (MODE == 0) {
      MFMA(acc0, va2[p], vbh0[p]);
      MFMA(acc0, va2[p], vbl0[p]);
      MFMA(acc1, va2[p], vbh1[p]);
      MFMA(acc1, va2[p], vbl1[p]);
    }
    if (s + 4 < 32) {
      const int k0 = (s + 4) * 32;
      va[p]   = *(const bf16x8*)(pA   + k0);
      vbh0[p] = *(const bf16x8*)(pBh0 + k0);
      vbl0[p] = *(const bf16x8*)(pBl0 + k0);
      vbh1[p] = *(const bf16x8*)(pBh1 + k0);
      vbl1[p] = *(const bf16x8*)(pBl1 + k0);
      if constexpr (MODE == 0) va2[p] = *(const bf16x8*)(pA2 + k0);
    }
  }

  // epilogue (identical to R4): y = acc*pf; clip [0,sl]; k = rint(y*Tq/sl)
  const float Tqf = tq_val(tqp);
  const float sl  = scales[l];
  const float pf  = (l == 0) ? 1.0f : scales[l - 1] / Tqf;
  const float rq  = Tqf / sl;
  const float fq  = sl / Tqf;

  f32x4 accs[2] = {acc0, acc1};
  #pragma unroll
  for (int fn = 0; fn < 2; ++fn) {
    const int ocl = wn * 32 + fn * 16 + ln;      // C/D col = lane&15
    #pragma unroll
    for (int rr = 0; rr < 4; ++rr) {
      const int br = b0 + wm * 16 + g * 4 + rr;  // C/D row = 4*(lane>>4)+reg
      float y = accs[fn][rr] * pf;
      y = fminf(fmaxf(y, 0.0f), sl);
      float kq = rintf(y * rq);
      if constexpr (MODE == 2) {
        if (ocl < n_out) out[(size_t)br * n_out + ocl] = kq * fq;
      } else {
        Hout[(size_t)br * N_DIM + (o0 + ocl)] = f2bf(kq);
      }
    }
  }
}

extern "C" void kernel_launch(void* const* d_in, const int* in_sizes, int n_in,
                              void* d_out, int out_size, void* d_ws, size_t ws_size,
                              hipStream_t stream) {
  const float* x      = (const float*)d_in[0];
  const float* W      = (const float*)d_in[1];
  const int*   gidx   = (const int*)d_in[2];
  const float* scales = (const float*)d_in[3];
  const int*   oidx   = (const int*)d_in[4];
  const int*   tqp    = (const int*)d_in[5];
  float*       out    = (float*)d_out;
  const int L     = in_sizes[3];
  const int n_out = in_sizes[4];
  const size_t NN = (size_t)N_DIM * N_DIM;

  u16* Whi = (u16*)d_ws;
  u16* Wlo = Whi + (size_t)L * NN;
  u16* G0h = Wlo + (size_t)L * NN;
  u16* G0l = G0h + NN;
  u16* G   = G0l + NN;
  u16* H   = G + NN;

  wsplit_k<<<2048, 256, 0, stream>>>(W, Whi, Wlo, (int)(L * NN / 4));
  xsplit_k<<<1024, 256, 0, stream>>>(x, gidx, G0h, G0l);

  gemm_k<0><<<256, THREADS, 0, stream>>>(
      G0h, G0l, Whi, Wlo, nullptr, scales, tqp, 0, n_out, H, nullptr);

  for (int l = 1; l < L; ++l) {
    gather_k<<<256, 256, 0, stream>>>(H, gidx + (size_t)l * N_DIM, G);
    if (l < L - 1) {
      gemm_k<1><<<256, THREADS, 0, stream>>>(
          G, nullptr, Whi + (size_t)l * NN, Wlo + (size_t)l * NN,
          nullptr, scales, tqp, l, n_out, H, nullptr);
    } else {
      gemm_k<2><<<16, THREADS, 0, stream>>>(
          G, nullptr, Whi + (size_t)l * NN, Wlo + (size_t)l * NN,
          oidx, scales, tqp, l, n_out, nullptr, out);
    }
  }
}

// Round 8
// 549.728 us; speedup vs baseline: 4.9978x; 2.1072x over previous
//
#include <hip/hip_runtime.h>
#include <hip/hip_bf16.h>

// UnifiedCoreFlow: 24x { gather-cols -> GEMM(1024^3) -> clip -> quantize } -> 10-col gather.
// R8 synthesis of R4/R5/R6 evidence:
//   R4 28us (LDS, shallow prefetch) | R5 121us (LDS ring, HBM over-fetch + 1wg/CU convoy)
//   R6 38us (no LDS -> 4x L2 request amplification).
// Fix: LDS staging (dedup) + XCD-exclusive o-panels (W from HBM once) + 2 wg/CU
// co-residency (grid 512, 256 thr, 64KB LDS) + counted-vmcnt 4-stage ring (1 barrier/step).
// Numerics: per-output accumulation order identical to R4 (absmax 0.0).

#define N_DIM   1024
#define NSTEP   16          // K / BK, BK = 64
#define THREADS 256

typedef __attribute__((ext_vector_type(8))) __bf16 bf16x8;
typedef __attribute__((ext_vector_type(4))) float  f32x4;
typedef unsigned short u16;

__device__ __forceinline__ u16 f2bf(float f) {
  __hip_bfloat16 h = __float2bfloat16(f);
  return __builtin_bit_cast(u16, h);
}
__device__ __forceinline__ float bf2f(u16 u) {
  __hip_bfloat16 h = __builtin_bit_cast(__hip_bfloat16, u);
  return __bfloat162float(h);
}
__device__ __forceinline__ float tq_val(const int* p) {
  int v = *p;
  if (v >= 1 && v <= (1 << 24)) return (float)v;
  return __builtin_bit_cast(float, v);
}
__device__ __forceinline__ void gload16(const void* g, char* l) {
  __builtin_amdgcn_global_load_lds(
      (const __attribute__((address_space(1))) unsigned int*)g,
      (__attribute__((address_space(3))) unsigned int*)l, 16, 0, 0);
}
template <int N>
__device__ __forceinline__ void wait_vm() {
  asm volatile("s_waitcnt vmcnt(%0)" :: "n"(N) : "memory");
}
#define MFMA(d, va, vb) d = __builtin_amdgcn_mfma_f32_16x16x32_bf16(va, vb, d, 0, 0, 0)

// ---- one-time W split: fp32 -> bf16 hi + lo ------------------------------
__global__ __launch_bounds__(256)
void wsplit_k(const float* __restrict__ W, u16* __restrict__ Wh,
              u16* __restrict__ Wl, int n4) {
  int i = blockIdx.x * blockDim.x + threadIdx.x;
  const int stride = gridDim.x * blockDim.x;
  for (; i < n4; i += stride) {
    float4 v = ((const float4*)W)[i];
    ushort4 h, l;
    h.x = f2bf(v.x); l.x = f2bf(v.x - bf2f(h.x));
    h.y = f2bf(v.y); l.y = f2bf(v.y - bf2f(h.y));
    h.z = f2bf(v.z); l.z = f2bf(v.z - bf2f(h.z));
    h.w = f2bf(v.w); l.w = f2bf(v.w - bf2f(h.w));
    ((ushort4*)Wh)[i] = h;
    ((ushort4*)Wl)[i] = l;
  }
}

// ---- layer-0 pre-pass: gather x by idx0, split hi/lo ---------------------
__global__ __launch_bounds__(256)
void xsplit_k(const float* __restrict__ x, const int* __restrict__ gidx0,
              u16* __restrict__ G0h, u16* __restrict__ G0l) {
  __shared__ float row[N_DIM];
  const int b = blockIdx.x, t = threadIdx.x;
  *(float4*)&row[t * 4] = *(const float4*)&x[(size_t)b * N_DIM + t * 4];
  __syncthreads();
  const int i0 = t * 4;
  const int4 c = *(const int4*)&gidx0[i0];
  float v0 = row[c.x], v1 = row[c.y], v2 = row[c.z], v3 = row[c.w];
  u16 h0 = f2bf(v0), h1 = f2bf(v1), h2 = f2bf(v2), h3 = f2bf(v3);
  u16 l0 = f2bf(v0 - bf2f(h0)), l1 = f2bf(v1 - bf2f(h1));
  u16 l2 = f2bf(v2 - bf2f(h2)), l3 = f2bf(v3 - bf2f(h3));
  *(ushort4*)&G0h[(size_t)b * N_DIM + i0] = make_ushort4(h0, h1, h2, h3);
  *(ushort4*)&G0l[(size_t)b * N_DIM + i0] = make_ushort4(l0, l1, l2, l3);
}

// ---- per-layer gather: G = H[:, idx] (bf16 k-values, exact) --------------
__global__ __launch_bounds__(256)
void gather_k(const u16* __restrict__ H, const int* __restrict__ idx,
              u16* __restrict__ G) {
  __shared__ u16 rows[4][N_DIM];
  const int t = threadIdx.x;
  const int r0 = blockIdx.x * 4;
  const int4* src = (const int4*)(H + (size_t)r0 * N_DIM);
  int4* dst = (int4*)&rows[0][0];
  dst[t] = src[t];
  dst[t + 256] = src[t + 256];
  __syncthreads();
  const int4 iv = *(const int4*)&idx[t * 4];
  #pragma unroll
  for (int rr = 0; rr < 4; ++rr) {
    ushort4 o;
    o.x = rows[rr][iv.x]; o.y = rows[rr][iv.y];
    o.z = rows[rr][iv.z]; o.w = rows[rr][iv.w];
    *(ushort4*)&G[(size_t)(r0 + rr) * N_DIM + t * 4] = o;
  }
}

// ---- pipelined GEMM, 64b x 32o per wg ------------------------------------
// MODE 0: A = G0h+G0l (layer 0). 1: mid. 2: last (B rows = W[oidx], 16 wgs).
// Stage (bytes): A [64r][8 chunk16] @0 (8K) [, A2 @8K (mode0)], Bh (4K), Bl (4K).
// 4-stage ring; counted vmcnt; 1 barrier/step; both-sides chunk XOR swizzle (c^(r&7)).
template <int MODE>
__global__ __launch_bounds__(THREADS, 1)
void gemm_k(const u16* __restrict__ A0, const u16* __restrict__ A1,
            const u16* __restrict__ Wh, const u16* __restrict__ Wl,
            const int* __restrict__ oidx,
            const float* __restrict__ scales, const int* __restrict__ tqp,
            int l, int n_out,
            u16* __restrict__ Hout, float* __restrict__ out) {
  constexpr int LOADS = (MODE == 0) ? 6 : 4;
  constexpr int STAGE = (MODE == 0) ? 24576 : 16384;
  constexpr int BH_OFF = (MODE == 0) ? 16384 : 8192;
  constexpr int BL_OFF = BH_OFF + 4096;
  extern __shared__ char sm[];

  const int t = threadIdx.x;
  const int i = blockIdx.x;
  int b0, o0;
  if constexpr (MODE == 2) {
    b0 = i * 64; o0 = 0;
  } else {
    // XCD-exclusive: XCD (i&7) owns o-tiles {4*(i&7) .. 4*(i&7)+3} (32-wide), all b.
    const int xcd = i & 7, j = i >> 3;        // j in [0,64)
    o0 = (xcd * 4 + (j & 3)) * 32;
    b0 = (j >> 2) * 64;                       // 16 b-tiles
  }

  // --- staging source pointers (pre-swizzled global chunks) ---
  // A elems e in {t, t+256}: row r=e>>3 (0..63), chunk c=e&7 -> src chunk c^(r&7).
  const int rA0 = t >> 3,        cA0 = (t & 7) ^ (rA0 & 7);
  const int rA1 = (t + 256) >> 3, cA1 = (t & 7) ^ (rA1 & 7);
  const int rB  = t >> 3;                                   // 0..31 (t<256)
  const int cB  = (t & 7) ^ (rB & 7);
  const u16* gA0a = A0 + (size_t)(b0 + rA0) * N_DIM + cA0 * 8;
  const u16* gA0b = A0 + (size_t)(b0 + rA1) * N_DIM + cA1 * 8;
  const u16* gA1a = nullptr; const u16* gA1b = nullptr;
  if constexpr (MODE == 0) {
    gA1a = A1 + (size_t)(b0 + rA0) * N_DIM + cA0 * 8;
    gA1b = A1 + (size_t)(b0 + rA1) * N_DIM + cA1 * 8;
  }
  int orow = o0 + rB;
  if constexpr (MODE == 2) orow = oidx[rB < n_out ? rB : 0];
  const u16* gBh = Wh + (size_t)orow * N_DIM + cB * 8;
  const u16* gBl = Wl + (size_t)orow * N_DIM + cB * 8;

  auto issue = [&](int st) {
    char* base = sm + (st & 3) * STAGE;
    const int k0 = st * 64;                    // halves along k
    gload16(gA0a + k0, base + t * 16);
    gload16(gA0b + k0, base + (t + 256) * 16);
    if constexpr (MODE == 0) {
      gload16(gA1a + k0, base + 8192 + t * 16);
      gload16(gA1b + k0, base + 8192 + (t + 256) * 16);
    }
    gload16(gBh + k0, base + BH_OFF + t * 16);
    gload16(gBl + k0, base + BL_OFF + t * 16);
  };

  // --- fragment offsets: wave (wm=w&1: 32 b-rows, wn=w>>1: 16 o) ---
  const int lane = t & 63, w = t >> 6;
  const int ln = lane & 15, g = lane >> 4;
  const int wm = w & 1, wn = w >> 1;
  const int ra0 = wm * 32 + ln, ra1 = wm * 32 + 16 + ln;   // A rows (sub 0,1)
  const int rb  = wn * 16 + ln;                            // B row
  // chunk for (kk,g) = kk*4+g, swizzled by row&7 (= ln&7 since offsets are mult of 8)
  const int sw = ln & 7;
  const int aoff00 = ra0 * 128 + ((0 + g) ^ sw) * 16;      // sub0, kk0
  const int aoff01 = ra0 * 128 + ((4 + g) ^ sw) * 16;      // sub0, kk1
  const int aoff10 = ra1 * 128 + ((0 + g) ^ sw) * 16;
  const int aoff11 = ra1 * 128 + ((4 + g) ^ sw) * 16;
  const int boff0  = rb  * 128 + ((0 + g) ^ sw) * 16;
  const int boff1  = rb  * 128 + ((4 + g) ^ sw) * 16;

  issue(0); issue(1); issue(2);

  f32x4 acc0 = {0.f, 0.f, 0.f, 0.f};
  f32x4 acc1 = {0.f, 0.f, 0.f, 0.f};

  for (int s = 0; s < NSTEP; ++s) {
    if (s < NSTEP - 2)       wait_vm<2 * LOADS>();
    else if (s == NSTEP - 2) wait_vm<LOADS>();
    else                     wait_vm<0>();
    __builtin_amdgcn_s_barrier();
    __builtin_amdgcn_sched_barrier(0);
    if (s + 3 < NSTEP) issue(s + 3);           // overwrites buf[(s-1)&3]: safe post-barrier

    const char* base = sm + (s & 3) * STAGE;
    // kk = 0
    {
      bf16x8 a0 = *(const bf16x8*)(base + aoff00);
      bf16x8 a1 = *(const bf16x8*)(base + aoff10);
      bf16x8 bh = *(const bf16x8*)(base + BH_OFF + boff0);
      bf16x8 bl = *(const bf16x8*)(base + BL_OFF + boff0);
      MFMA(acc0, a0, bh); MFMA(acc0, a0, bl);
      MFMA(acc1, a1, bh); MFMA(acc1, a1, bl);
      if constexpr (MODE == 0) {
        bf16x8 c0 = *(const bf16x8*)(base + 8192 + aoff00);
        bf16x8 c1 = *(const bf16x8*)(base + 8192 + aoff10);
        MFMA(acc0, c0, bh); MFMA(acc0, c0, bl);
        MFMA(acc1, c1, bh); MFMA(acc1, c1, bl);
      }
    }
    // kk = 1
    {
      bf16x8 a0 = *(const bf16x8*)(base + aoff01);
      bf16x8 a1 = *(const bf16x8*)(base + aoff11);
      bf16x8 bh = *(const bf16x8*)(base + BH_OFF + boff1);
      bf16x8 bl = *(const bf16x8*)(base + BL_OFF + boff1);
      MFMA(acc0, a0, bh); MFMA(acc0, a0, bl);
      MFMA(acc1, a1, bh); MFMA(acc1, a1, bl);
      if constexpr (MODE == 0) {
        bf16x8 c0 = *(const bf16x8*)(base + 8192 + aoff01);
        bf16x8 c1 = *(const bf16x8*)(base + 8192 + aoff11);
        MFMA(acc0, c0, bh); MFMA(acc0, c0, bl);
        MFMA(acc1, c1, bh); MFMA(acc1, c1, bl);
      }
    }
  }

  // epilogue (identical to R4): y = acc*pf; clip [0,sl]; k = rint(y*Tq/sl)
  const float Tqf = tq_val(tqp);
  const float sl  = scales[l];
  const float pf  = (l == 0) ? 1.0f : scales[l - 1] / Tqf;
  const float rq  = Tqf / sl;
  const float fq  = sl / Tqf;

  f32x4 accs[2] = {acc0, acc1};
  const int ocl = wn * 16 + ln;                 // C/D col = lane&15
  #pragma unroll
  for (int sub = 0; sub < 2; ++sub) {
    #pragma unroll
    for (int rr = 0; rr < 4; ++rr) {
      const int br = b0 + wm * 32 + sub * 16 + g * 4 + rr;  // C/D row = 4*(lane>>4)+reg
      float y = accs[sub][rr] * pf;
      y = fminf(fmaxf(y, 0.0f), sl);
      float kq = rintf(y * rq);
      if constexpr (MODE == 2) {
        if (ocl < n_out) out[(size_t)br * n_out + ocl] = kq * fq;
      } else {
        Hout[(size_t)br * N_DIM + (o0 + ocl)] = f2bf(kq);
      }
    }
  }
}

extern "C" void kernel_launch(void* const* d_in, const int* in_sizes, int n_in,
                              void* d_out, int out_size, void* d_ws, size_t ws_size,
                              hipStream_t stream) {
  const float* x      = (const float*)d_in[0];
  const float* W      = (const float*)d_in[1];
  const int*   gidx   = (const int*)d_in[2];
  const float* scales = (const float*)d_in[3];
  const int*   oidx   = (const int*)d_in[4];
  const int*   tqp    = (const int*)d_in[5];
  float*       out    = (float*)d_out;
  const int L     = in_sizes[3];
  const int n_out = in_sizes[4];
  const size_t NN = (size_t)N_DIM * N_DIM;

  u16* Whi = (u16*)d_ws;
  u16* Wlo = Whi + (size_t)L * NN;
  u16* G0h = Wlo + (size_t)L * NN;
  u16* G0l = G0h + NN;
  u16* G   = G0l + NN;
  u16* H   = G + NN;

  hipFuncSetAttribute((const void*)&gemm_k<0>, hipFuncAttributeMaxDynamicSharedMemorySize, 98304);
  hipFuncSetAttribute((const void*)&gemm_k<1>, hipFuncAttributeMaxDynamicSharedMemorySize, 65536);
  hipFuncSetAttribute((const void*)&gemm_k<2>, hipFuncAttributeMaxDynamicSharedMemorySize, 65536);

  wsplit_k<<<2048, 256, 0, stream>>>(W, Whi, Wlo, (int)(L * NN / 4));
  xsplit_k<<<1024, 256, 0, stream>>>(x, gidx, G0h, G0l);

  gemm_k<0><<<512, THREADS, 98304, stream>>>(
      G0h, G0l, Whi, Wlo, nullptr, scales, tqp, 0, n_out, H, nullptr);

  for (int l = 1; l < L; ++l) {
    gather_k<<<256, 256, 0, stream>>>(H, gidx + (size_t)l * N_DIM, G);
    if (l < L - 1) {
      gemm_k<1><<<512, THREADS, 65536, stream>>>(
          G, nullptr, Whi + (size_t)l * NN, Wlo + (size_t)l * NN,
          nullptr, scales, tqp, l, n_out, H, nullptr);
    } else {
      gemm_k<2><<<16, THREADS, 65536, stream>>>(
          G, nullptr, Whi + (size_t)l * NN, Wlo + (size_t)l * NN,
          oidx, scales, tqp, l, n_out, nullptr, out);
    }
  }
}